// Round 1
// baseline (315.545 us; speedup 1.0000x reference)
//
#include <hip/hip_runtime.h>
#include <math.h>

// B=64, Q=4096, N=256, 20 fg classes + 1 bg. Output (B,Q,N) fp32 = 268 MB.
// KEY SPARSITY FACT: centers uniform in [0,50]^3, gate radius 2.0 ->
// P(dist<=2) ~ 0.027%; P(any of a wave-iter's 256 pairs active) ~ 6.5%.
// 93% of wave-iters are pure MISS. Strategy: split the bulk 1e6 store
// (memset-rate fill kernel, dependency-free store stream) from the gate
// compute (store-free fast path, sparse fixup stores only).
#define BQ 64
#define QQ 4096
#define NN 256
#define NC 20
#define NL 21
#define TQ 256          // queries per block
#define GEO_STRIDE 12   // 10 floats used + 2 pad -> 48 B, 16-B aligned (ds_read_b128)
#define PROB_STRIDE 257 // label gather hits distinct banks; staging writes conflict-free

// Gate: sqrt_rn(d2) <= 2.0  <=>  d2 <= 4 + ulp(4)  (bit-exact vs numpy fp32).
#define GATE_D2 0x1.000001p+2f

// ---- Kernel 1: bulk MISS fill. Pure back-to-back float4 stores, no
// dependencies -> should match fillBufferAligned's ~5.9 TB/s. 2048 blocks
// = 8 blocks/CU = full 32-wave occupancy.
__global__ __launch_bounds__(256)
void fill_kernel(float4* __restrict__ out, int n4) {
    const float4 MISS = make_float4(1000000.0f, 1000000.0f, 1000000.0f, 1000000.0f);
    int i = blockIdx.x * 256 + threadIdx.x;
    const int stride = gridDim.x * 256;
    for (; i < n4; i += stride) out[i] = MISS;
}

// ---- Kernel 2: gate compute + sparse fixups. No stores on the ~93% of
// wave-iters that are all-MISS; per-lane predicated float4 store otherwise
// (inactive j slots within an active lane's quad are 1e6, bit-identical to
// the fill, so overwriting them is harmless).
__global__ __launch_bounds__(256)
void matcher_kernel(const float* __restrict__ logits,
                    const float* __restrict__ pboxes,
                    const int*   __restrict__ tlabels,
                    const float* __restrict__ tboxes,
                    float* __restrict__ out) {
    __shared__ __align__(16) float geo[TQ * GEO_STRIDE];    // 12 KB
    __shared__ float prob[NC * PROB_STRIDE];                // 20.1 KB
    const int tid = threadIdx.x;
    const int b   = blockIdx.y;
    const int q0  = blockIdx.x * TQ;

    // ---- staging: one q per thread (softmax once per q) ----
    {
        const int q = q0 + tid;
        const float* lg = logits + (size_t)(b * QQ + q) * NL;
        float l[NL];
        #pragma unroll
        for (int c = 0; c < NL; ++c) l[c] = lg[c];
        float m = l[0];
        #pragma unroll
        for (int c = 1; c < NL; ++c) m = fmaxf(m, l[c]);
        float e[NL];
        float s = 0.f;
        #pragma unroll
        for (int c = 0; c < NL; ++c) { e[c] = expf(l[c] - m); s += e[c]; }
        const float rs = 1.0f / s;
        #pragma unroll
        for (int c = 0; c < NC; ++c)    // bank (c+tid)%32 -> 2 lanes/bank (free)
            prob[c * PROB_STRIDE + tid] = -(e[c] * rs);

        const float* pb = pboxes + (size_t)(b * QQ + q) * 6;
        const float pcx = pb[0], pcy = pb[1], pcz = pb[2];
        const float psx = pb[3], psy = pb[4], psz = pb[5];
        float4* gp = (float4*)(geo + tid * GEO_STRIDE);
        gp[0] = make_float4(pcx, pcy, pcz, psx * psy * psz);
        gp[1] = make_float4(pcx - psx * 0.5f, pcy - psy * 0.5f, pcz - psz * 0.5f, 0.f);
        gp[2] = make_float4(pcx + psx * 0.5f, pcy + psy * 0.5f, pcz + psz * 0.5f, 0.f);
    }

    // ---- per-thread: quad of targets n0..n0+3 in registers ----
    const int lane = tid & 63;
    const int w    = tid >> 6;
    const int n0   = lane * 4;
    float tcx[4], tcy[4], tcz[4];
    float mn_x[4], mn_y[4], mn_z[4], mx_x[4], mx_y[4], mx_z[4], v2[4];
    int plab[4];
    #pragma unroll
    for (int j = 0; j < 4; ++j) {
        const float* tb = tboxes + (size_t)(b * NN + n0 + j) * 6;
        const float cx = tb[0], cy = tb[1], cz = tb[2];
        const float sx = tb[3], sy = tb[4], sz = tb[5];
        tcx[j] = cx; tcy[j] = cy; tcz[j] = cz;
        mn_x[j] = cx - sx * 0.5f; mn_y[j] = cy - sy * 0.5f; mn_z[j] = cz - sz * 0.5f;
        mx_x[j] = cx + sx * 0.5f; mx_y[j] = cy + sy * 0.5f; mx_z[j] = cz + sz * 0.5f;
        v2[j]   = sx * sy * sz;
        plab[j] = tlabels[b * NN + n0 + j] * PROB_STRIDE;
    }

    __syncthreads();

    float* ob = out + ((size_t)(b * QQ + q0)) * NN + n0;

    // Each wave handles qq = w, w+4, ... Fast path (~93% of iters): d2 +
    // gate only, NO store (fill kernel already wrote the MISS row).
    for (int qq = w; qq < TQ; qq += 4) {
        const float4* gp = (const float4*)(geo + qq * GEO_STRIDE); // uniform broadcast
        const float4 g0 = gp[0];   // pc.xyz, vol1

        // strict fp32, numpy op order, no FMA: feeds the 1e6 discontinuity gate
        float d2v[4];
        int active = 0;
        #pragma unroll
        for (int j = 0; j < 4; ++j) {
            const float dx = __fsub_rn(g0.x, tcx[j]);
            const float dy = __fsub_rn(g0.y, tcy[j]);
            const float dz = __fsub_rn(g0.z, tcz[j]);
            d2v[j] = __fadd_rn(__fadd_rn(__fmul_rn(dx, dx), __fmul_rn(dy, dy)),
                               __fmul_rn(dz, dz));
            active |= (d2v[j] <= GATE_D2);
        }

        if (!__any(active)) continue;  // wave-uniform: ~93% of iters, store-free

        const float4 g1 = gp[1];       // min1.xyz
        const float4 g2 = gp[2];       // max1.xyz
        float r[4];
        #pragma unroll
        for (int j = 0; j < 4; ++j) {
            const float negp = prob[plab[j] + qq];

            const float dist = __builtin_amdgcn_sqrtf(d2v[j]); // continuous term only

            const float ix = fmaxf(fminf(g2.x, mx_x[j]) - fmaxf(g1.x, mn_x[j]), 0.f);
            const float iy = fmaxf(fminf(g2.y, mx_y[j]) - fmaxf(g1.y, mn_y[j]), 0.f);
            const float iz = fmaxf(fminf(g2.z, mx_z[j]) - fmaxf(g1.z, mn_z[j]), 0.f);
            const float iv  = ix * iy * iz;
            const float uni = g0.w + v2[j] - iv;     // > 0 always (sizes >= 0.5)
            const float iou = iv * __builtin_amdgcn_rcpf(uni);

            const float t = fmaf(5.0f, dist, negp) + fmaf(-2.0f, iou, 2.0f);
            r[j] = (d2v[j] <= GATE_D2) ? t : 1000000.0f;   // bit-exact gate
        }
        if (active) {                  // per-lane sparse fixup (~0.03% of pairs)
            float4* orow = (float4*)(ob + (size_t)qq * NN);
            *orow = make_float4(r[0], r[1], r[2], r[3]);
        }
    }
}

extern "C" void kernel_launch(void* const* d_in, const int* in_sizes, int n_in,
                              void* d_out, int out_size, void* d_ws, size_t ws_size,
                              hipStream_t stream) {
    const float* logits  = (const float*)d_in[0];  // (B,Q,21)
    const float* pboxes  = (const float*)d_in[1];  // (B,Q,6)
    const int*   tlabels = (const int*)d_in[2];    // (B,N)
    const float* tboxes  = (const float*)d_in[3];  // (B,N,6)
    float* out = (float*)d_out;                    // (B,Q,N) fp32

    const int n4 = (BQ * QQ * NN) / 4;             // 16,777,216 float4s = 268 MB
    fill_kernel<<<dim3(2048), dim3(256), 0, stream>>>((float4*)out, n4);

    dim3 grid(QQ / TQ, BQ);                        // 16 x 64 = 1024 blocks = 4/CU
    matcher_kernel<<<grid, dim3(256), 0, stream>>>(logits, pboxes, tlabels, tboxes, out);
}

// Round 4
// 314.769 us; speedup vs baseline: 1.0025x; 1.0025x over previous
//
#include <hip/hip_runtime.h>
#include <math.h>

// B=64, Q=4096, N=256, 20 fg classes + 1 bg. Output (B,Q,N) fp32 = 268 MB.
// KEY SPARSITY FACT: centers uniform in [0,50]^3, gate radius 2.0 ->
// P(dist<=2) ~ 0.027%; P(any of a wave-iter's 256 pairs active) ~ 6.5%.
// 93% of wave-iters take a d2-only fast path and store constant 1e6.
//
// R1 lesson (A/B): separate fill kernel (+43us) vs storeless matcher (-22us)
// = net loss -> stores are already overlapped; matcher is latency-bound.
// R2/R3: kill the 20-KB prob LDS + the 84-B-stride logits gather by moving
// the softmax into the rare slow path (wave-uniform single-line loads). LDS
// 32.1 -> 12.3 KB, launch_bounds(256,6) -> 24 waves/CU (was 16).
// R3: pragma unroll 1 on the qq loop (guard against code-size blowup).
#define BQ 64
#define QQ 4096
#define NN 256
#define NC 20
#define NL 21
#define TQ 256          // queries per block
#define GEO_STRIDE 12   // 10 floats used + 2 pad -> 48 B, 16-B aligned (ds_read_b128)

// Gate: sqrt_rn(d2) <= 2.0  <=>  d2 <= 4 + ulp(4)  (bit-exact vs numpy fp32).
#define GATE_D2 0x1.000001p+2f

__global__ __launch_bounds__(256, 6)
void matcher_kernel(const float* __restrict__ logits,
                    const float* __restrict__ pboxes,
                    const int*   __restrict__ tlabels,
                    const float* __restrict__ tboxes,
                    float* __restrict__ out) {
    __shared__ __align__(16) float geo[TQ * GEO_STRIDE];    // 12.3 KB total LDS
    const int tid = threadIdx.x;
    const int b   = blockIdx.y;
    const int q0  = blockIdx.x * TQ;

    // ---- staging: one q per thread, geometry only (no softmax here) ----
    {
        const int q = q0 + tid;
        const float2* pb = (const float2*)(pboxes + (size_t)(b * QQ + q) * 6);
        const float2 p01 = pb[0], p23 = pb[1], p45 = pb[2];
        const float pcx = p01.x, pcy = p01.y, pcz = p23.x;
        const float psx = p23.y, psy = p45.x, psz = p45.y;
        float4* gp = (float4*)(geo + tid * GEO_STRIDE);
        gp[0] = make_float4(pcx, pcy, pcz, psx * psy * psz);
        gp[1] = make_float4(pcx - psx * 0.5f, pcy - psy * 0.5f, pcz - psz * 0.5f, 0.f);
        gp[2] = make_float4(pcx + psx * 0.5f, pcy + psy * 0.5f, pcz + psz * 0.5f, 0.f);
    }

    // ---- per-thread: quad of targets n0..n0+3 in registers ----
    const int lane = tid & 63;
    const int w    = tid >> 6;
    const int n0   = lane * 4;
    float tcx[4], tcy[4], tcz[4];
    float mn_x[4], mn_y[4], mn_z[4], mx_x[4], mx_y[4], mx_z[4], v2[4];
    int lab[4];
    #pragma unroll
    for (int j = 0; j < 4; ++j) {
        const float2* tb = (const float2*)(tboxes + (size_t)(b * NN + n0 + j) * 6);
        const float2 t01 = tb[0], t23 = tb[1], t45 = tb[2];
        const float cx = t01.x, cy = t01.y, cz = t23.x;
        const float sx = t23.y, sy = t45.x, sz = t45.y;
        tcx[j] = cx; tcy[j] = cy; tcz[j] = cz;
        mn_x[j] = cx - sx * 0.5f; mn_y[j] = cy - sy * 0.5f; mn_z[j] = cz - sz * 0.5f;
        mx_x[j] = cx + sx * 0.5f; mx_y[j] = cy + sy * 0.5f; mx_z[j] = cz + sz * 0.5f;
        v2[j]   = sx * sy * sz;
        lab[j]  = tlabels[b * NN + n0 + j];
    }

    __syncthreads();

    const float4 MISS = make_float4(1000000.0f, 1000000.0f, 1000000.0f, 1000000.0f);
    float* ob = out + ((size_t)(b * QQ + q0)) * NN + n0;

    // Each wave handles qq = w, w+4, ... One dwordx4 store per wave-iter
    // covers a contiguous 1-KB q-row (coalesced). Fast path: d2 + gate only.
    #pragma unroll 1
    for (int qq = w; qq < TQ; qq += 4) {
        const float4* gp = (const float4*)(geo + qq * GEO_STRIDE); // uniform broadcast
        const float4 g0 = gp[0];   // pc.xyz, vol1

        // strict fp32, numpy op order, no FMA: feeds the 1e6 discontinuity gate
        float d2v[4];
        int active = 0;
        #pragma unroll
        for (int j = 0; j < 4; ++j) {
            const float dx = __fsub_rn(g0.x, tcx[j]);
            const float dy = __fsub_rn(g0.y, tcy[j]);
            const float dz = __fsub_rn(g0.z, tcz[j]);
            d2v[j] = __fadd_rn(__fadd_rn(__fmul_rn(dx, dx), __fmul_rn(dy, dy)),
                               __fmul_rn(dz, dz));
            active |= (d2v[j] <= GATE_D2);
        }

        float4* orow = (float4*)(ob + (size_t)qq * NN);
        if (!__any(active)) {          // wave-uniform: ~93% of iters
            *orow = MISS;
            continue;
        }

        // ---- slow path (~6.5% of wave-iters): softmax for q=q0+qq,
        // recomputed from a wave-uniform logits row (1-2 cache lines).
        // Bit-exact: same expf, same serial sum order, same 1/s, same -(e*rs)
        // as the verified staged version.
        const float* lg = logits + (size_t)(b * QQ + q0 + qq) * NL;
        float e[NL];
        #pragma unroll
        for (int c = 0; c < NL; ++c) e[c] = lg[c];
        float m = e[0];
        #pragma unroll
        for (int c = 1; c < NL; ++c) m = fmaxf(m, e[c]);
        float s = 0.f;
        #pragma unroll
        for (int c = 0; c < NL; ++c) { e[c] = expf(e[c] - m); s += e[c]; }
        const float rs = 1.0f / s;

        const float4 g1 = gp[1];       // min1.xyz
        const float4 g2 = gp[2];       // max1.xyz
        float r[4];
        #pragma unroll
        for (int j = 0; j < 4; ++j) {
            // e[label] via compile-time-indexed select tree (no scratch)
            float ev = e[0];
            #pragma unroll
            for (int c = 1; c < NC; ++c) ev = (lab[j] == c) ? e[c] : ev;
            const float negp = -(ev * rs);

            const float dist = __builtin_amdgcn_sqrtf(d2v[j]); // continuous term only

            const float ix = fmaxf(fminf(g2.x, mx_x[j]) - fmaxf(g1.x, mn_x[j]), 0.f);
            const float iy = fmaxf(fminf(g2.y, mx_y[j]) - fmaxf(g1.y, mn_y[j]), 0.f);
            const float iz = fmaxf(fminf(g2.z, mx_z[j]) - fmaxf(g1.z, mn_z[j]), 0.f);
            const float iv  = ix * iy * iz;
            const float uni = g0.w + v2[j] - iv;     // > 0 always (sizes >= 0.5)
            const float iou = iv * __builtin_amdgcn_rcpf(uni);

            const float t = fmaf(5.0f, dist, negp) + fmaf(-2.0f, iou, 2.0f);
            r[j] = (d2v[j] <= GATE_D2) ? t : 1000000.0f;   // bit-exact gate
        }
        *orow = make_float4(r[0], r[1], r[2], r[3]);
    }
}

extern "C" void kernel_launch(void* const* d_in, const int* in_sizes, int n_in,
                              void* d_out, int out_size, void* d_ws, size_t ws_size,
                              hipStream_t stream) {
    const float* logits  = (const float*)d_in[0];  // (B,Q,21)
    const float* pboxes  = (const float*)d_in[1];  // (B,Q,6)
    const int*   tlabels = (const int*)d_in[2];    // (B,N)
    const float* tboxes  = (const float*)d_in[3];  // (B,N,6)
    float* out = (float*)d_out;                    // (B,Q,N) fp32

    dim3 grid(QQ / TQ, BQ);                        // 16 x 64 = 1024 blocks
    matcher_kernel<<<grid, dim3(256), 0, stream>>>(logits, pboxes, tlabels, tboxes, out);
}

// Round 5
// 297.474 us; speedup vs baseline: 1.0607x; 1.0581x over previous
//
#include <hip/hip_runtime.h>
#include <math.h>

// B=64, Q=4096, N=256, 20 fg classes + 1 bg. Output (B,Q,N) fp32 = 268 MB.
// KEY SPARSITY FACT: centers uniform in [0,50]^3, gate radius 2.0 ->
// P(dist<=2) ~ 0.027%; P(a q-row of 256 pairs has any active) ~ 6.5%.
//
// Ledger: R0 fused+staged softmax = 294.9 (matcher ~114us). R1 split
// fill/storeless = 315.5 -> stores are overlapped, not the limiter.
// R2-R4 softmax-in-slow-path + launch_bounds(256,6) = 314.8 -> spills +
// expf recompute cost 20us; REVERTED to R0 structure.
// R5: 4 q-rows per wave-iter (ILP on the ds_read->d2->ballot->store chain,
// which is the latency-bound critical path at 16 waves/CU). Arithmetic
// per (q,n) pair is bit-identical to R0; only iteration grouping changed.
#define BQ 64
#define QQ 4096
#define NN 256
#define NC 20
#define NL 21
#define TQ 256          // queries per block
#define GEO_STRIDE 12   // 10 floats used + 2 pad -> 48 B, 16-B aligned (ds_read_b128)
#define PROB_STRIDE 257 // label gather hits distinct banks; staging writes conflict-free

// Gate: sqrt_rn(d2) <= 2.0  <=>  d2 <= 4 + ulp(4)  (bit-exact vs numpy fp32).
#define GATE_D2 0x1.000001p+2f

__global__ __launch_bounds__(256)
void matcher_kernel(const float* __restrict__ logits,
                    const float* __restrict__ pboxes,
                    const int*   __restrict__ tlabels,
                    const float* __restrict__ tboxes,
                    float* __restrict__ out) {
    __shared__ __align__(16) float geo[TQ * GEO_STRIDE];    // 12 KB
    __shared__ float prob[NC * PROB_STRIDE];                // 20.1 KB
    const int tid = threadIdx.x;
    const int b   = blockIdx.y;
    const int q0  = blockIdx.x * TQ;

    // ---- staging: one q per thread (softmax once per q) ----
    {
        const int q = q0 + tid;
        const float* lg = logits + (size_t)(b * QQ + q) * NL;
        float l[NL];
        #pragma unroll
        for (int c = 0; c < NL; ++c) l[c] = lg[c];
        float m = l[0];
        #pragma unroll
        for (int c = 1; c < NL; ++c) m = fmaxf(m, l[c]);
        float e[NL];
        float s = 0.f;
        #pragma unroll
        for (int c = 0; c < NL; ++c) { e[c] = expf(l[c] - m); s += e[c]; }
        const float rs = 1.0f / s;
        #pragma unroll
        for (int c = 0; c < NC; ++c)    // bank (c+tid)%32 -> 2 lanes/bank (free)
            prob[c * PROB_STRIDE + tid] = -(e[c] * rs);

        const float* pb = pboxes + (size_t)(b * QQ + q) * 6;
        const float pcx = pb[0], pcy = pb[1], pcz = pb[2];
        const float psx = pb[3], psy = pb[4], psz = pb[5];
        float4* gp = (float4*)(geo + tid * GEO_STRIDE);
        gp[0] = make_float4(pcx, pcy, pcz, psx * psy * psz);
        gp[1] = make_float4(pcx - psx * 0.5f, pcy - psy * 0.5f, pcz - psz * 0.5f, 0.f);
        gp[2] = make_float4(pcx + psx * 0.5f, pcy + psy * 0.5f, pcz + psz * 0.5f, 0.f);
    }

    // ---- per-thread: quad of targets n0..n0+3 in registers ----
    const int lane = tid & 63;
    const int w    = tid >> 6;
    const int n0   = lane * 4;
    float tcx[4], tcy[4], tcz[4];
    float mn_x[4], mn_y[4], mn_z[4], mx_x[4], mx_y[4], mx_z[4], v2[4];
    int plab[4];
    #pragma unroll
    for (int j = 0; j < 4; ++j) {
        const float* tb = tboxes + (size_t)(b * NN + n0 + j) * 6;
        const float cx = tb[0], cy = tb[1], cz = tb[2];
        const float sx = tb[3], sy = tb[4], sz = tb[5];
        tcx[j] = cx; tcy[j] = cy; tcz[j] = cz;
        mn_x[j] = cx - sx * 0.5f; mn_y[j] = cy - sy * 0.5f; mn_z[j] = cz - sz * 0.5f;
        mx_x[j] = cx + sx * 0.5f; mx_y[j] = cy + sy * 0.5f; mx_z[j] = cz + sz * 0.5f;
        v2[j]   = sx * sy * sz;
        plab[j] = tlabels[b * NN + n0 + j] * PROB_STRIDE;
    }

    __syncthreads();

    const float4 MISS = make_float4(1000000.0f, 1000000.0f, 1000000.0f, 1000000.0f);
    float* ob = out + ((size_t)(b * QQ + q0)) * NN + n0;

    // Wave w handles row-quads {4w+16k}. Per iter: 4 independent ds_read_b128
    // + 4 independent d2 chains + ONE ballot + 4 coalesced 1-KB row stores
    // (4 KB contiguous per wave-iter). 16 iters/wave.
    #pragma unroll 1
    for (int qq = w * 4; qq < TQ; qq += 16) {
        float4 g0[4];
        #pragma unroll
        for (int rr = 0; rr < 4; ++rr)
            g0[rr] = ((const float4*)(geo + (qq + rr) * GEO_STRIDE))[0]; // pc.xyz, vol1

        // strict fp32, numpy op order, no FMA: feeds the 1e6 discontinuity gate
        float d2v[4][4];
        int act = 0;
        #pragma unroll
        for (int rr = 0; rr < 4; ++rr) {
            #pragma unroll
            for (int j = 0; j < 4; ++j) {
                const float dx = __fsub_rn(g0[rr].x, tcx[j]);
                const float dy = __fsub_rn(g0[rr].y, tcy[j]);
                const float dz = __fsub_rn(g0[rr].z, tcz[j]);
                d2v[rr][j] = __fadd_rn(__fadd_rn(__fmul_rn(dx, dx), __fmul_rn(dy, dy)),
                                       __fmul_rn(dz, dz));
                act |= (d2v[rr][j] <= GATE_D2) << rr;
            }
        }

        if (!__any(act)) {             // ~76% of wave-iters: 4 MISS rows
            #pragma unroll
            for (int rr = 0; rr < 4; ++rr)
                *(float4*)(ob + (size_t)(qq + rr) * NN) = MISS;
            continue;
        }

        #pragma unroll
        for (int rr = 0; rr < 4; ++rr) {
            float4* orow = (float4*)(ob + (size_t)(qq + rr) * NN);
            if (!__any((act >> rr) & 1)) {   // this row all-miss
                *orow = MISS;
                continue;
            }
            // ---- slow path: verbatim R0 per-row compute (bit-exact) ----
            const float4* gp = (const float4*)(geo + (qq + rr) * GEO_STRIDE);
            const float4 g1 = gp[1];   // min1.xyz
            const float4 g2 = gp[2];   // max1.xyz
            float r[4];
            #pragma unroll
            for (int j = 0; j < 4; ++j) {
                const float negp = prob[plab[j] + qq + rr];

                const float dist = __builtin_amdgcn_sqrtf(d2v[rr][j]);

                const float ix = fmaxf(fminf(g2.x, mx_x[j]) - fmaxf(g1.x, mn_x[j]), 0.f);
                const float iy = fmaxf(fminf(g2.y, mx_y[j]) - fmaxf(g1.y, mn_y[j]), 0.f);
                const float iz = fmaxf(fminf(g2.z, mx_z[j]) - fmaxf(g1.z, mn_z[j]), 0.f);
                const float iv  = ix * iy * iz;
                const float uni = g0[rr].w + v2[j] - iv;   // > 0 always (sizes >= 0.5)
                const float iou = iv * __builtin_amdgcn_rcpf(uni);

                const float t = fmaf(5.0f, dist, negp) + fmaf(-2.0f, iou, 2.0f);
                r[j] = (d2v[rr][j] <= GATE_D2) ? t : 1000000.0f;   // bit-exact gate
            }
            *orow = make_float4(r[0], r[1], r[2], r[3]);
        }
    }
}

extern "C" void kernel_launch(void* const* d_in, const int* in_sizes, int n_in,
                              void* d_out, int out_size, void* d_ws, size_t ws_size,
                              hipStream_t stream) {
    const float* logits  = (const float*)d_in[0];  // (B,Q,21)
    const float* pboxes  = (const float*)d_in[1];  // (B,Q,6)
    const int*   tlabels = (const int*)d_in[2];    // (B,N)
    const float* tboxes  = (const float*)d_in[3];  // (B,N,6)
    float* out = (float*)d_out;                    // (B,Q,N) fp32

    dim3 grid(QQ / TQ, BQ);                        // 16 x 64 = 1024 blocks = 4/CU
    matcher_kernel<<<grid, dim3(256), 0, stream>>>(logits, pboxes, tlabels, tboxes, out);
}